// Round 4
// baseline (2334.694 us; speedup 1.0000x reference)
//
#include <hip/hip_runtime.h>

typedef _Float16 f16;
typedef _Float16 half2t __attribute__((ext_vector_type(2)));
typedef _Float16 half8 __attribute__((ext_vector_type(8)));
typedef float f32x4 __attribute__((ext_vector_type(4)));

#define KP 320
#define DIN 300
#define SRAW 1024
#define SSUM 128

// ---------------- workspace layout (bytes) ----------------
static constexpr size_t OFF_XG_RAW  = 0;                                        // f16 [2][32][1024][1024] (u*4+gate interleave)
static constexpr size_t OFF_XG_SUM  = OFF_XG_RAW + (size_t)2*32*1024*1024*2;    // f16 [2][32][128][1024]
static constexpr size_t OFF_OUT_RAW = OFF_XG_SUM + (size_t)2*32*128*1024*2;     // f16 [32][1024][512]
static constexpr size_t OFF_OUT_SUM = OFF_OUT_RAW + (size_t)32*1024*512*2;      // f16 [32][128][512]
static constexpr size_t OFF_A_RAW   = OFF_OUT_SUM + (size_t)32*128*512*2;       // f16 [32768][320]
static constexpr size_t OFF_A_SUM   = OFF_A_RAW + (size_t)32768*KP*2;           // f16 [4096][320]
static constexpr size_t OFF_BIH_RAW = OFF_A_SUM + (size_t)4096*KP*2;            // f16 [2048][320]
static constexpr size_t OFF_BIH_SUM = OFF_BIH_RAW + (size_t)2048*KP*2;          // f16 [2048][320]
static constexpr size_t OFF_WHH     = OFF_BIH_SUM + (size_t)2048*KP*2;          // f16 [4][64][512][8] chunk layout
static constexpr size_t OFF_WQ      = OFF_WHH + (size_t)4*64*512*8*2;           // f16 [512][512]
static constexpr size_t OFF_KB      = OFF_WQ + (size_t)512*512*2;               // f32 [4][32][128]
static constexpr size_t OFF_VB      = OFF_KB + (size_t)4*32*128*4;              // f32 [4][32][128]
static constexpr size_t OFF_ATTN    = OFF_VB + (size_t)4*32*128*4;              // f32 [4][32][1024]
static constexpr size_t WS_NEED     = OFF_ATTN + (size_t)4*32*1024*4;           // ~208 MB

// ---------------- pack / convert ----------------
// Whh chunk layout: [ed][c(64)][t(512)][8 f16], where for thread t (rg=t>>3, ks=t&7)
// chunk c = j*4+q holds W[rg*16+j][ks*32+q*8 .. +8)  -- j in [0,16), q in [0,4)
__global__ void pack_kernel(
    const float* __restrict__ in_raw, const float* __restrict__ in_sum,
    const float* __restrict__ wih_rf, const float* __restrict__ wih_rb,
    const float* __restrict__ wih_sf, const float* __restrict__ wih_sb,
    const float* __restrict__ whh_rf, const float* __restrict__ whh_rb,
    const float* __restrict__ whh_sf, const float* __restrict__ whh_sb,
    const float* __restrict__ wq,
    f16* __restrict__ a_raw, f16* __restrict__ a_sum,
    f16* __restrict__ bih_raw, f16* __restrict__ bih_sum,
    f16* __restrict__ whh16, f16* __restrict__ wq16)
{
  constexpr size_t N1 = (size_t)32768*KP;
  constexpr size_t N2 = (size_t)4096*KP;
  constexpr size_t N3 = (size_t)2048*KP;
  constexpr size_t N5 = (size_t)4*64*512*8;
  constexpr size_t N6 = (size_t)512*512;
  const size_t TOT = N1+N2+N3+N3+N5+N6;
  const size_t stride = (size_t)gridDim.x*blockDim.x;
  for (size_t i = (size_t)blockIdx.x*blockDim.x + threadIdx.x; i < TOT; i += stride) {
    size_t j = i;
    if (j < N1) {
      size_t m = j/KP, k = j - m*KP;
      a_raw[j] = (f16)(k < DIN ? in_raw[m*DIN + k] : 0.f);
      continue;
    }
    j -= N1;
    if (j < N2) {
      size_t m = j/KP, k = j - m*KP;
      a_sum[j] = (f16)(k < DIN ? in_sum[m*DIN + k] : 0.f);
      continue;
    }
    j -= N2;
    if (j < N3) {
      size_t n = j/KP, k = j - n*KP;
      float v = 0.f;
      if (k < DIN) v = (n < 1024) ? wih_rf[n*DIN + k] : wih_rb[(n-1024)*DIN + k];
      bih_raw[j] = (f16)v;
      continue;
    }
    j -= N3;
    if (j < N3) {
      size_t n = j/KP, k = j - n*KP;
      float v = 0.f;
      if (k < DIN) v = (n < 1024) ? wih_sf[n*DIN + k] : wih_sb[(n-1024)*DIN + k];
      bih_sum[j] = (f16)v;
      continue;
    }
    j -= N3;
    if (j < N5) {
      int ed = (int)(j >> 18);
      int c  = (int)((j >> 12) & 63);
      int t  = (int)((j >> 3) & 511);
      int ii = (int)(j & 7);
      int jrow = c >> 2, q = c & 3;
      int rg = t >> 3, ks = t & 7;
      int row = rg*16 + jrow;
      int col = ks*32 + q*8 + ii;
      const float* src = (ed==0)?whh_rf:(ed==1)?whh_rb:(ed==2)?whh_sf:whh_sb;
      whh16[j] = (f16)src[(size_t)row*256 + col];
      continue;
    }
    j -= N5;
    {
      int n = (int)(j >> 9), k = (int)(j & 511);
      int h = n >> 7, dh = n & 127;
      wq16[j] = (f16)wq[((size_t)h*512 + k)*128 + dh];
    }
  }
}

// ---------------- f16 MFMA GEMM: C[M,N] = A[M,K] * B[N,K]^T ----------------
// EPI 0: plain f32 store.  EPI 1: +bias, f16 store to xg, [u*4+gate] interleave.
template<int EPI>
__global__ __launch_bounds__(256) void gemm_kernel(
    const f16* __restrict__ A, const f16* __restrict__ Bm,
    float* __restrict__ Cf, f16* __restrict__ Cx,
    const float* __restrict__ bias0, const float* __restrict__ bias1,
    int K, int ldcN, size_t dirStride)
{
  __shared__ __align__(16) f16 As[128*40];
  __shared__ __align__(16) f16 Bs[128*40];
  const int tid = threadIdx.x;
  const int m0 = blockIdx.x*128, n0 = blockIdx.y*128;
  const int w = tid >> 6, lane = tid & 63;
  const int wm = w >> 1, wn = w & 1;
  const int lr = lane & 15, lk = lane >> 4;
  f32x4 acc[4][4] = {};
  const int nsteps = K >> 5;
  for (int kt = 0; kt < nsteps; ++kt) {
    __syncthreads();
    #pragma unroll
    for (int it = 0; it < 2; ++it) {
      int c = tid + it*256;
      int r = c >> 2, kc = c & 3;
      *(uint4*)&As[r*40 + kc*8] = *(const uint4*)&A[(size_t)(m0+r)*K + kt*32 + kc*8];
      *(uint4*)&Bs[r*40 + kc*8] = *(const uint4*)&Bm[(size_t)(n0+r)*K + kt*32 + kc*8];
    }
    __syncthreads();
    half8 af[4], bf[4];
    #pragma unroll
    for (int mt = 0; mt < 4; ++mt) af[mt] = *(const half8*)&As[(wm*64 + mt*16 + lr)*40 + lk*8];
    #pragma unroll
    for (int nt = 0; nt < 4; ++nt) bf[nt] = *(const half8*)&Bs[(wn*64 + nt*16 + lr)*40 + lk*8];
    #pragma unroll
    for (int mt = 0; mt < 4; ++mt)
      #pragma unroll
      for (int nt = 0; nt < 4; ++nt)
        acc[mt][nt] = __builtin_amdgcn_mfma_f32_16x16x32_f16(af[mt], bf[nt], acc[mt][nt], 0, 0, 0);
  }
  const int rb = lk*4;
  #pragma unroll
  for (int mt = 0; mt < 4; ++mt) {
    #pragma unroll
    for (int nt = 0; nt < 4; ++nt) {
      int n = n0 + wn*64 + nt*16 + lr;
      int mloc = m0 + wm*64 + mt*16 + rb;
      if (EPI == 0) {
        #pragma unroll
        for (int r = 0; r < 4; ++r)
          Cf[(size_t)(mloc+r)*ldcN + n] = acc[mt][nt][r];
      } else {
        int dir = n >> 10, cc = n & 1023;
        int gate = cc >> 8, u = cc & 255;
        float bs = (dir ? bias1 : bias0)[cc];
        f16* dst = Cx + (size_t)dir*dirStride;
        #pragma unroll
        for (int r = 0; r < 4; ++r)
          dst[(size_t)(mloc+r)*1024 + u*4 + gate] = (f16)(acc[mt][nt][r] + bs);
      }
    }
  }
}

// ---------------- LSTM recurrence (lane k-sliced) ----------------
// 1 WG (512 threads) per (e,d,b). Thread t: rg=t>>3 (row group), ks=t&7 (k-slice of 32).
// Rows r = rg*16+j, j=0..15: j<10 register-resident, j=10..12 LDS, j=13..15 L2-streamed.
#define RROWS 10
#define LROWS 3

__device__ __forceinline__ float dot8(float acc, uint4 wv, uint4 hv) {
#if __has_builtin(__builtin_amdgcn_fdot2)
  union { uint4 u; half2t h[4]; } W, Hh;
  W.u = wv; Hh.u = hv;
  #pragma unroll
  for (int i = 0; i < 4; ++i) acc = __builtin_amdgcn_fdot2(W.h[i], Hh.h[i], acc, false);
#else
  union { uint4 u; f16 h[8]; } W, Hh;
  W.u = wv; Hh.u = hv;
  #pragma unroll
  for (int i = 0; i < 8; ++i) acc += (float)W.h[i]*(float)Hh.h[i];
#endif
  return acc;
}

__device__ __forceinline__ float sigmoid_f(float x) {
  float e = __expf(-x);
  return __builtin_amdgcn_rcpf(1.f + e);
}
__device__ __forceinline__ float tanh_f(float x) {
  float e = __expf(2.f * x);
  return 1.f - 2.f * __builtin_amdgcn_rcpf(e + 1.f);
}

__device__ __forceinline__ void pin4(uint4& v) {
  asm volatile("" : "+v"(v.x), "+v"(v.y), "+v"(v.z), "+v"(v.w));
}

// DPP butterfly add over the 8-lane k-slice group (VALU pipe, no LDS).
template<int CTRL>
__device__ __forceinline__ float dpp_add(float v) {
  int m = __builtin_amdgcn_update_dpp(0, __builtin_bit_cast(int, v), CTRL, 0xf, 0xf, true);
  return v + __builtin_bit_cast(float, m);
}
__device__ __forceinline__ float reduce8(float v) {
  v = dpp_add<0xB1>(v);   // quad_perm [1,0,3,2]  : lane ^ 1
  v = dpp_add<0x4E>(v);   // quad_perm [2,3,0,1]  : lane ^ 2
  v = dpp_add<0x141>(v);  // row_half_mirror      : cross 4-group within 8
  return v;
}

__global__ void __launch_bounds__(512) __attribute__((amdgpu_waves_per_eu(2, 2)))
lstm_kernel(
    const f16* __restrict__ whh16,
    const f16* __restrict__ xg_raw, const f16* __restrict__ xg_sum,
    f16* __restrict__ out_raw, f16* __restrict__ out_sum)
{
  const int wg = blockIdx.x;               // [e(1)][d(1)][b(5)]
  const int e = wg >> 6, r2 = wg & 63, d = r2 >> 5, b = r2 & 31;
  const int S = e ? SSUM : SRAW;
  const int t = threadIdx.x;
  const int rg = t >> 3, ks = t & 7;
  const uint4* wb = (const uint4*)(whh16 + (size_t)(e*2+d)*(64*512*8));
  const f16* xg = (e ? xg_sum : xg_raw) + ((size_t)(d*32 + b))*(size_t)S*1024;
  f16* outp = (e ? out_sum : out_raw) + (size_t)b*S*512 + d*256;

  __shared__ __align__(16) uint4 wl[LROWS*4*512];   // 96 KB: rows 10..12
  __shared__ float pre[1024];                        // [gate][u] raw pre-acts
  __shared__ __align__(16) f16 hrep[4*264];          // 4 padded copies of h[256]

  // stage LDS weight rows
  #pragma unroll
  for (int c = 0; c < LROWS*4; ++c) wl[c*512 + t] = wb[(RROWS*4 + c)*512 + t];
  // register weight rows (pinned so they can't be rematerialized by reloads)
  uint4 wr[RROWS*4];
  #pragma unroll
  for (int c = 0; c < RROWS*4; ++c) wr[c] = wb[c*512 + t];
  #pragma unroll
  for (int c = 0; c < RROWS*4; ++c) pin4(wr[c]);

  if (t < 256) {
    #pragma unroll
    for (int cpy = 0; cpy < 4; ++cpy) hrep[cpy*264 + t] = (f16)0.f;
  }
  float cst = 0.f;
  const int hbyte = (ks >> 1)*528 + ks*64;           // conflict-free slice base
  const int preS = ((rg >> 4) << 8) + ((rg & 15) << 4);  // gate*256 + ubase
  __syncthreads();

  for (int st = 0; st < S; ++st) {
    const int s = d ? (S - 1 - st) : st;
    // stop LICM from hoisting the loop-invariant-address streamed loads
    asm volatile("" ::: "memory");

    // xg for this step (tail threads), consumed after the barrier
    uint2 xq;
    if (t < 256) xq = *(const uint2*)(xg + ((size_t)s*1024 + t*4));

    // streamed weight rows 13,14 issue now (row 15 later) — L2-resident
    uint4 gA[4], gB[4], gC[4];
    #pragma unroll
    for (int q = 0; q < 4; ++q) gA[q] = wb[(52 + q)*512 + t];
    #pragma unroll
    for (int q = 0; q < 4; ++q) gB[q] = wb[(56 + q)*512 + t];

    // h slice (32 elems) from replicated copy — conflict-free
    uint4 hv[4];
    #pragma unroll
    for (int q = 0; q < 4; ++q)
      hv[q] = *(const uint4*)((const char*)hrep + hbyte + q*16);

    float pa = 0.f, pb = 0.f;   // owned rows: j=ks and j=ks+8

    // register rows 0..9
    #pragma unroll
    for (int j = 0; j < RROWS; ++j) {
      float rs = 0.f;
      #pragma unroll
      for (int q = 0; q < 4; ++q) rs = dot8(rs, wr[j*4 + q], hv[q]);
      rs = reduce8(rs);
      if (j < 8) { pa = (ks == j) ? rs : pa; }
      else       { pb = (ks == j - 8) ? rs : pb; }
    }
    // issue stream row 15
    #pragma unroll
    for (int q = 0; q < 4; ++q) gC[q] = wb[(60 + q)*512 + t];
    // LDS rows 10..12
    #pragma unroll
    for (int j = RROWS; j < RROWS + LROWS; ++j) {
      float rs = 0.f;
      #pragma unroll
      for (int q = 0; q < 4; ++q) rs = dot8(rs, wl[((j - RROWS)*4 + q)*512 + t], hv[q]);
      rs = reduce8(rs);
      pb = (ks == j - 8) ? rs : pb;
    }
    // streamed rows 13..15
    {
      float rs = 0.f;
      #pragma unroll
      for (int q = 0; q < 4; ++q) rs = dot8(rs, gA[q], hv[q]);
      rs = reduce8(rs);
      pb = (ks == 5) ? rs : pb;
    }
    {
      float rs = 0.f;
      #pragma unroll
      for (int q = 0; q < 4; ++q) rs = dot8(rs, gB[q], hv[q]);
      rs = reduce8(rs);
      pb = (ks == 6) ? rs : pb;
    }
    {
      float rs = 0.f;
      #pragma unroll
      for (int q = 0; q < 4; ++q) rs = dot8(rs, gC[q], hv[q]);
      rs = reduce8(rs);
      pb = (ks == 7) ? rs : pb;
    }

    pre[preS + ks]     = pa;
    pre[preS + 8 + ks] = pb;
    __syncthreads();

    if (t < 256) {
      half2t x01 = __builtin_bit_cast(half2t, xq.x);  // i, f
      half2t x23 = __builtin_bit_cast(half2t, xq.y);  // g, o
      float vi = pre[t]       + (float)x01[0];
      float vf = pre[256 + t] + (float)x01[1];
      float vg = pre[512 + t] + (float)x23[0];
      float vo = pre[768 + t] + (float)x23[1];
      float ig = sigmoid_f(vi);
      float fg = sigmoid_f(vf);
      float gg = tanh_f(vg);
      float og = sigmoid_f(vo);
      cst = fg*cst + ig*gg;
      float hval = og*tanh_f(cst);
      f16 hf = (f16)hval;
      #pragma unroll
      for (int cpy = 0; cpy < 4; ++cpy) hrep[cpy*264 + t] = hf;
      outp[(size_t)s*512 + t] = hf;
    }
    __syncthreads();
  }
}

// ---------------- mean pool + k,v projection ----------------
__global__ __launch_bounds__(256) void pool_kv_kernel(
    const f16* __restrict__ out_sum, const int* __restrict__ len_sum,
    const float* __restrict__ Wk, const float* __restrict__ Wv,
    float* __restrict__ kb, float* __restrict__ vb)
{
  const int b = blockIdx.x, t = threadIdx.x;
  __shared__ float sv[512];
  int len = len_sum[b]; if (len < 1) len = 1;
  float a0 = 0.f, a1 = 0.f;
  for (int s = 0; s < len; ++s) {
    const f16* row = out_sum + ((size_t)b*SSUM + s)*512;
    a0 += (float)row[t];
    a1 += (float)row[t+256];
  }
  float inv = 1.f/(float)len;
  sv[t] = a0*inv; sv[t+256] = a1*inv;
  __syncthreads();
  #pragma unroll
  for (int half = 0; half < 2; ++half) {
    int o = t + half*256;
    int h = o >> 7, dh = o & 127;
    const float* wkp = Wk + (size_t)h*512*128 + dh;
    const float* wvp = Wv + (size_t)h*512*128 + dh;
    float ak = 0.f, av = 0.f;
    for (int e2 = 0; e2 < 512; ++e2) {
      float sve = sv[e2];
      ak += sve*wkp[(size_t)e2*128];
      av += sve*wvp[(size_t)e2*128];
    }
    kb[((size_t)h*32 + b)*128 + dh] = ak;
    vb[((size_t)h*32 + b)*128 + dh] = av;
  }
}

// ---------------- scores + softmax ----------------
__global__ __launch_bounds__(256) void attn_kernel(
    const float* __restrict__ q, const float* __restrict__ kb, float* __restrict__ attn)
{
  const int hb = blockIdx.x;          // h*32 + b
  const int h = hb >> 5, b = hb & 31;
  const int t = threadIdx.x;
  __shared__ __align__(16) float kk[128];
  __shared__ float red[4];
  if (t < 128) kk[t] = kb[(size_t)hb*128 + t];
  __syncthreads();
  float vals[4];
  #pragma unroll
  for (int i = 0; i < 4; ++i) {
    int s = t + i*256;
    const float4* qp = (const float4*)(q + ((size_t)b*1024 + s)*512 + h*128);
    const float4* kp = (const float4*)kk;
    float a = 0.f;
    #pragma unroll
    for (int e2 = 0; e2 < 32; ++e2) {
      float4 qq = qp[e2], kx = kp[e2];
      a += qq.x*kx.x + qq.y*kx.y + qq.z*kx.z + qq.w*kx.w;
    }
    vals[i] = a;
  }
  float m = fmaxf(fmaxf(vals[0], vals[1]), fmaxf(vals[2], vals[3]));
  for (int o = 1; o < 64; o <<= 1) m = fmaxf(m, __shfl_xor(m, o));
  if ((t & 63) == 0) red[t >> 6] = m;
  __syncthreads();
  m = fmaxf(fmaxf(red[0], red[1]), fmaxf(red[2], red[3]));
  __syncthreads();
  float ex[4], lsum = 0.f;
  #pragma unroll
  for (int i = 0; i < 4; ++i) { ex[i] = __expf(vals[i] - m); lsum += ex[i]; }
  for (int o = 1; o < 64; o <<= 1) lsum += __shfl_xor(lsum, o);
  if ((t & 63) == 0) red[t >> 6] = lsum;
  __syncthreads();
  float inv = 1.f/(red[0] + red[1] + red[2] + red[3]);
  #pragma unroll
  for (int i = 0; i < 4; ++i) attn[(size_t)hb*1024 + t + i*256] = ex[i]*inv;
}

// ---------------- final: out = q + attn * v ----------------
__global__ __launch_bounds__(256) void final_kernel(
    float* __restrict__ out, const float* __restrict__ attn, const float* __restrict__ vb)
{
  const size_t TOT4 = (size_t)32*1024*512/4;
  const size_t stride = (size_t)gridDim.x*blockDim.x;
  for (size_t i = (size_t)blockIdx.x*blockDim.x + threadIdx.x; i < TOT4; i += stride) {
    int c4 = (int)(i & 127);
    int h = c4 >> 5;
    size_t srow = i >> 7;
    int b = (int)(srow >> 10), s = (int)(srow & 1023);
    float a = attn[((size_t)h*32 + b)*1024 + s];
    float4 vv = ((const float4*)vb)[((size_t)h*32 + b)*32 + (c4 & 31)];
    float4 qq = ((float4*)out)[i];
    qq.x += a*vv.x; qq.y += a*vv.y; qq.z += a*vv.z; qq.w += a*vv.w;
    ((float4*)out)[i] = qq;
  }
}

// ---------------- launch ----------------
extern "C" void kernel_launch(void* const* d_in, const int* in_sizes, int n_in,
                              void* d_out, int out_size, void* d_ws, size_t ws_size,
                              hipStream_t stream)
{
  const float* in_raw = (const float*)d_in[0];
  const float* in_sum = (const float*)d_in[1];
  const int*  len_sum = (const int*)d_in[3];
  const float* rf_wih = (const float*)d_in[4];
  const float* rf_whh = (const float*)d_in[5];
  const float* rf_b   = (const float*)d_in[6];
  const float* rb_wih = (const float*)d_in[7];
  const float* rb_whh = (const float*)d_in[8];
  const float* rb_b   = (const float*)d_in[9];
  const float* sf_wih = (const float*)d_in[10];
  const float* sf_whh = (const float*)d_in[11];
  const float* sf_b   = (const float*)d_in[12];
  const float* sb_wih = (const float*)d_in[13];
  const float* sb_whh = (const float*)d_in[14];
  const float* sb_b   = (const float*)d_in[15];
  const float* wq     = (const float*)d_in[16];
  const float* wk     = (const float*)d_in[17];
  const float* wv     = (const float*)d_in[18];

  if (ws_size < WS_NEED) return;

  char* ws = (char*)d_ws;
  f16* xg_raw_p  = (f16*)(ws + OFF_XG_RAW);
  f16* xg_sum_p  = (f16*)(ws + OFF_XG_SUM);
  f16* out_raw_p = (f16*)(ws + OFF_OUT_RAW);
  f16* out_sum_p = (f16*)(ws + OFF_OUT_SUM);
  f16* a_raw_p   = (f16*)(ws + OFF_A_RAW);
  f16* a_sum_p   = (f16*)(ws + OFF_A_SUM);
  f16* bih_raw_p = (f16*)(ws + OFF_BIH_RAW);
  f16* bih_sum_p = (f16*)(ws + OFF_BIH_SUM);
  f16* whh16_p   = (f16*)(ws + OFF_WHH);
  f16* wq16_p    = (f16*)(ws + OFF_WQ);
  float* kb_p    = (float*)(ws + OFF_KB);
  float* vb_p    = (float*)(ws + OFF_VB);
  float* attn_p  = (float*)(ws + OFF_ATTN);
  float* qout    = (float*)d_out;

  pack_kernel<<<4096, 256, 0, stream>>>(
      in_raw, in_sum, rf_wih, rb_wih, sf_wih, sb_wih,
      rf_whh, rb_whh, sf_whh, sb_whh, wq,
      a_raw_p, a_sum_p, bih_raw_p, bih_sum_p, whh16_p, wq16_p);

  gemm_kernel<1><<<dim3(256, 16), 256, 0, stream>>>(
      a_raw_p, bih_raw_p, nullptr, xg_raw_p, rf_b, rb_b, KP, 0, (size_t)32*1024*1024);
  gemm_kernel<1><<<dim3(32, 16), 256, 0, stream>>>(
      a_sum_p, bih_sum_p, nullptr, xg_sum_p, sf_b, sb_b, KP, 0, (size_t)32*128*1024);

  lstm_kernel<<<128, 512, 0, stream>>>(whh16_p, xg_raw_p, xg_sum_p, out_raw_p, out_sum_p);

  gemm_kernel<0><<<dim3(256, 4), 256, 0, stream>>>(
      out_raw_p, wq16_p, qout, nullptr, nullptr, nullptr, 512, 512, 0);

  pool_kv_kernel<<<32, 256, 0, stream>>>(out_sum_p, len_sum, wk, wv, kb_p, vb_p);
  attn_kernel<<<128, 256, 0, stream>>>(qout, kb_p, attn_p);
  final_kernel<<<4096, 256, 0, stream>>>(qout, attn_p, vb_p);
}

// Round 5
// 2045.031 us; speedup vs baseline: 1.1416x; 1.1416x over previous
//
#include <hip/hip_runtime.h>

typedef _Float16 f16;
typedef _Float16 half2t __attribute__((ext_vector_type(2)));
typedef _Float16 half8 __attribute__((ext_vector_type(8)));
typedef float f32x4 __attribute__((ext_vector_type(4)));

#define KP 320
#define DIN 300
#define SRAW 1024
#define SSUM 128

// ---------------- workspace layout (bytes) ----------------
static constexpr size_t OFF_XG_RAW  = 0;                                        // f16 [2][32][1024][1024] (u*4+gate interleave)
static constexpr size_t OFF_XG_SUM  = OFF_XG_RAW + (size_t)2*32*1024*1024*2;    // f16 [2][32][128][1024]
static constexpr size_t OFF_OUT_RAW = OFF_XG_SUM + (size_t)2*32*128*1024*2;     // f16 [32][1024][512]
static constexpr size_t OFF_OUT_SUM = OFF_OUT_RAW + (size_t)32*1024*512*2;      // f16 [32][128][512]
static constexpr size_t OFF_A_RAW   = OFF_OUT_SUM + (size_t)32*128*512*2;       // f16 [32768][320]
static constexpr size_t OFF_A_SUM   = OFF_A_RAW + (size_t)32768*KP*2;           // f16 [4096][320]
static constexpr size_t OFF_BIH_RAW = OFF_A_SUM + (size_t)4096*KP*2;            // f16 [2048][320]
static constexpr size_t OFF_BIH_SUM = OFF_BIH_RAW + (size_t)2048*KP*2;          // f16 [2048][320]
static constexpr size_t OFF_WHH     = OFF_BIH_SUM + (size_t)2048*KP*2;          // f16 [4][64][512][8] chunk layout
static constexpr size_t OFF_WQ      = OFF_WHH + (size_t)4*64*512*8*2;           // f16 [512][512]
static constexpr size_t OFF_KB      = OFF_WQ + (size_t)512*512*2;               // f32 [4][32][128]
static constexpr size_t OFF_VB      = OFF_KB + (size_t)4*32*128*4;              // f32 [4][32][128]
static constexpr size_t OFF_ATTN    = OFF_VB + (size_t)4*32*128*4;              // f32 [4][32][1024]
static constexpr size_t WS_NEED     = OFF_ATTN + (size_t)4*32*1024*4;           // ~208 MB

// ---------------- pack / convert ----------------
// Whh chunk layout: [ed][c(64)][t(512)][8 f16], where for thread t (rg=t>>3, ks=t&7)
// chunk c = j*4+q holds W[rg*16+j][ks*32+q*8 .. +8)  -- j in [0,16), q in [0,4)
__global__ void pack_kernel(
    const float* __restrict__ in_raw, const float* __restrict__ in_sum,
    const float* __restrict__ wih_rf, const float* __restrict__ wih_rb,
    const float* __restrict__ wih_sf, const float* __restrict__ wih_sb,
    const float* __restrict__ whh_rf, const float* __restrict__ whh_rb,
    const float* __restrict__ whh_sf, const float* __restrict__ whh_sb,
    const float* __restrict__ wq,
    f16* __restrict__ a_raw, f16* __restrict__ a_sum,
    f16* __restrict__ bih_raw, f16* __restrict__ bih_sum,
    f16* __restrict__ whh16, f16* __restrict__ wq16)
{
  constexpr size_t N1 = (size_t)32768*KP;
  constexpr size_t N2 = (size_t)4096*KP;
  constexpr size_t N3 = (size_t)2048*KP;
  constexpr size_t N5 = (size_t)4*64*512*8;
  constexpr size_t N6 = (size_t)512*512;
  const size_t TOT = N1+N2+N3+N3+N5+N6;
  const size_t stride = (size_t)gridDim.x*blockDim.x;
  for (size_t i = (size_t)blockIdx.x*blockDim.x + threadIdx.x; i < TOT; i += stride) {
    size_t j = i;
    if (j < N1) {
      size_t m = j/KP, k = j - m*KP;
      a_raw[j] = (f16)(k < DIN ? in_raw[m*DIN + k] : 0.f);
      continue;
    }
    j -= N1;
    if (j < N2) {
      size_t m = j/KP, k = j - m*KP;
      a_sum[j] = (f16)(k < DIN ? in_sum[m*DIN + k] : 0.f);
      continue;
    }
    j -= N2;
    if (j < N3) {
      size_t n = j/KP, k = j - n*KP;
      float v = 0.f;
      if (k < DIN) v = (n < 1024) ? wih_rf[n*DIN + k] : wih_rb[(n-1024)*DIN + k];
      bih_raw[j] = (f16)v;
      continue;
    }
    j -= N3;
    if (j < N3) {
      size_t n = j/KP, k = j - n*KP;
      float v = 0.f;
      if (k < DIN) v = (n < 1024) ? wih_sf[n*DIN + k] : wih_sb[(n-1024)*DIN + k];
      bih_sum[j] = (f16)v;
      continue;
    }
    j -= N3;
    if (j < N5) {
      int ed = (int)(j >> 18);
      int c  = (int)((j >> 12) & 63);
      int t  = (int)((j >> 3) & 511);
      int ii = (int)(j & 7);
      int jrow = c >> 2, q = c & 3;
      int rg = t >> 3, ks = t & 7;
      int row = rg*16 + jrow;
      int col = ks*32 + q*8 + ii;
      const float* src = (ed==0)?whh_rf:(ed==1)?whh_rb:(ed==2)?whh_sf:whh_sb;
      whh16[j] = (f16)src[(size_t)row*256 + col];
      continue;
    }
    j -= N5;
    {
      int n = (int)(j >> 9), k = (int)(j & 511);
      int h = n >> 7, dh = n & 127;
      wq16[j] = (f16)wq[((size_t)h*512 + k)*128 + dh];
    }
  }
}

// ---------------- f16 MFMA GEMM: C[M,N] = A[M,K] * B[N,K]^T ----------------
// EPI 0: plain f32 store.  EPI 1: +bias, f16 store to xg, [u*4+gate] interleave.
template<int EPI>
__global__ __launch_bounds__(256) void gemm_kernel(
    const f16* __restrict__ A, const f16* __restrict__ Bm,
    float* __restrict__ Cf, f16* __restrict__ Cx,
    const float* __restrict__ bias0, const float* __restrict__ bias1,
    int K, int ldcN, size_t dirStride)
{
  __shared__ __align__(16) f16 As[128*40];
  __shared__ __align__(16) f16 Bs[128*40];
  const int tid = threadIdx.x;
  const int m0 = blockIdx.x*128, n0 = blockIdx.y*128;
  const int w = tid >> 6, lane = tid & 63;
  const int wm = w >> 1, wn = w & 1;
  const int lr = lane & 15, lk = lane >> 4;
  f32x4 acc[4][4] = {};
  const int nsteps = K >> 5;
  for (int kt = 0; kt < nsteps; ++kt) {
    __syncthreads();
    #pragma unroll
    for (int it = 0; it < 2; ++it) {
      int c = tid + it*256;
      int r = c >> 2, kc = c & 3;
      *(uint4*)&As[r*40 + kc*8] = *(const uint4*)&A[(size_t)(m0+r)*K + kt*32 + kc*8];
      *(uint4*)&Bs[r*40 + kc*8] = *(const uint4*)&Bm[(size_t)(n0+r)*K + kt*32 + kc*8];
    }
    __syncthreads();
    half8 af[4], bf[4];
    #pragma unroll
    for (int mt = 0; mt < 4; ++mt) af[mt] = *(const half8*)&As[(wm*64 + mt*16 + lr)*40 + lk*8];
    #pragma unroll
    for (int nt = 0; nt < 4; ++nt) bf[nt] = *(const half8*)&Bs[(wn*64 + nt*16 + lr)*40 + lk*8];
    #pragma unroll
    for (int mt = 0; mt < 4; ++mt)
      #pragma unroll
      for (int nt = 0; nt < 4; ++nt)
        acc[mt][nt] = __builtin_amdgcn_mfma_f32_16x16x32_f16(af[mt], bf[nt], acc[mt][nt], 0, 0, 0);
  }
  const int rb = lk*4;
  #pragma unroll
  for (int mt = 0; mt < 4; ++mt) {
    #pragma unroll
    for (int nt = 0; nt < 4; ++nt) {
      int n = n0 + wn*64 + nt*16 + lr;
      int mloc = m0 + wm*64 + mt*16 + rb;
      if (EPI == 0) {
        #pragma unroll
        for (int r = 0; r < 4; ++r)
          Cf[(size_t)(mloc+r)*ldcN + n] = acc[mt][nt][r];
      } else {
        int dir = n >> 10, cc = n & 1023;
        int gate = cc >> 8, u = cc & 255;
        float bs = (dir ? bias1 : bias0)[cc];
        f16* dst = Cx + (size_t)dir*dirStride;
        #pragma unroll
        for (int r = 0; r < 4; ++r)
          dst[(size_t)(mloc+r)*1024 + u*4 + gate] = (f16)(acc[mt][nt][r] + bs);
      }
    }
  }
}

// ---------------- LSTM recurrence (lane k-sliced) ----------------
// 1 WG (512 threads) per (e,d,b). Thread t: rg=t>>3 (row group), ks=t&7 (k-slice of 32).
// Rows r = rg*16+j, j=0..15: j<13 register-resident (208 dwords, pinned),
// j=13..15 read from LDS each step (96 KB, ~96 wave-b128 ≈ 1.1K cy on DS pipe,
// hidden under the ~1.7K cy VALU phase). No L2 streams, no memory clobber.
#define RROWS 13
#define LROWS 3

__device__ __forceinline__ float dot8(float acc, uint4 wv, uint4 hv) {
#if __has_builtin(__builtin_amdgcn_fdot2)
  union { uint4 u; half2t h[4]; } W, Hh;
  W.u = wv; Hh.u = hv;
  #pragma unroll
  for (int i = 0; i < 4; ++i) acc = __builtin_amdgcn_fdot2(W.h[i], Hh.h[i], acc, false);
#else
  union { uint4 u; f16 h[8]; } W, Hh;
  W.u = wv; Hh.u = hv;
  #pragma unroll
  for (int i = 0; i < 8; ++i) acc += (float)W.h[i]*(float)Hh.h[i];
#endif
  return acc;
}

__device__ __forceinline__ float sigmoid_f(float x) {
  float e = __expf(-x);
  return __builtin_amdgcn_rcpf(1.f + e);
}
__device__ __forceinline__ float tanh_f(float x) {
  float e = __expf(2.f * x);
  return 1.f - 2.f * __builtin_amdgcn_rcpf(e + 1.f);
}

__device__ __forceinline__ void pin4(uint4& v) {
  asm volatile("" : "+v"(v.x), "+v"(v.y), "+v"(v.z), "+v"(v.w));
}

// DPP butterfly add over the 8-lane k-slice group (VALU pipe, no LDS).
template<int CTRL>
__device__ __forceinline__ float dpp_add(float v) {
  int m = __builtin_amdgcn_update_dpp(0, __builtin_bit_cast(int, v), CTRL, 0xf, 0xf, true);
  return v + __builtin_bit_cast(float, m);
}
__device__ __forceinline__ float reduce8(float v) {
  v = dpp_add<0xB1>(v);   // quad_perm [1,0,3,2]  : lane ^ 1
  v = dpp_add<0x4E>(v);   // quad_perm [2,3,0,1]  : lane ^ 2
  v = dpp_add<0x141>(v);  // row_half_mirror      : cross 4-group within 8
  return v;
}

__global__ void __launch_bounds__(512) __attribute__((amdgpu_waves_per_eu(2, 2)))
lstm_kernel(
    const f16* __restrict__ whh16,
    const f16* __restrict__ xg_raw, const f16* __restrict__ xg_sum,
    f16* __restrict__ out_raw, f16* __restrict__ out_sum)
{
  const int wg = blockIdx.x;               // [e(1)][d(1)][b(5)]
  const int e = wg >> 6, r2 = wg & 63, d = r2 >> 5, b = r2 & 31;
  const int S = e ? SSUM : SRAW;
  const int t = threadIdx.x;
  const int rg = t >> 3, ks = t & 7;
  const uint4* wb = (const uint4*)(whh16 + (size_t)(e*2+d)*(64*512*8));
  const f16* xg = (e ? xg_sum : xg_raw) + ((size_t)(d*32 + b))*(size_t)S*1024;
  f16* outp = (e ? out_sum : out_raw) + (size_t)b*S*512 + d*256;

  __shared__ __align__(16) uint4 wl[LROWS*4*512];   // 96 KB: rows 13..15
  __shared__ float pre[1024];                        // [gate][u] raw pre-acts
  __shared__ __align__(16) f16 hrep[4*264];          // 4 padded copies of h[256]

  // stage LDS weight rows (chunks 52..63)
  #pragma unroll
  for (int c = 0; c < LROWS*4; ++c) wl[c*512 + t] = wb[(RROWS*4 + c)*512 + t];
  // register weight rows (pinned so they can't be rematerialized by reloads)
  uint4 wr[RROWS*4];
  #pragma unroll
  for (int c = 0; c < RROWS*4; ++c) wr[c] = wb[c*512 + t];
  #pragma unroll
  for (int c = 0; c < RROWS*4; ++c) pin4(wr[c]);

  if (t < 256) {
    #pragma unroll
    for (int cpy = 0; cpy < 4; ++cpy) hrep[cpy*264 + t] = (f16)0.f;
  }
  float cst = 0.f;
  const int hbyte = (ks >> 1)*528 + ks*64;           // conflict-free slice base
  const int preS = ((rg >> 4) << 8) + ((rg & 15) << 4);  // gate*256 + ubase
  __syncthreads();

  for (int st = 0; st < S; ++st) {
    const int s = d ? (S - 1 - st) : st;

    // xg for this step (tail threads), consumed after the barrier
    uint2 xq;
    if (t < 256) xq = *(const uint2*)(xg + ((size_t)s*1024 + t*4));

    // h slice (32 elems) from replicated copy — conflict-free
    uint4 hv[4];
    #pragma unroll
    for (int q = 0; q < 4; ++q)
      hv[q] = *(const uint4*)((const char*)hrep + hbyte + q*16);

    float pa = 0.f, pb = 0.f;   // owned rows: j=ks and j=ks+8

    // register rows 0..12
    #pragma unroll
    for (int j = 0; j < RROWS; ++j) {
      float rs = 0.f;
      #pragma unroll
      for (int q = 0; q < 4; ++q) rs = dot8(rs, wr[j*4 + q], hv[q]);
      rs = reduce8(rs);
      if (j < 8) { pa = (ks == j) ? rs : pa; }
      else       { pb = (ks == j - 8) ? rs : pb; }
    }
    // LDS rows 13..15 (per-lane-distinct b128 reads; compiler pipelines lgkmcnt)
    #pragma unroll
    for (int j = 0; j < LROWS; ++j) {
      float rs = 0.f;
      #pragma unroll
      for (int q = 0; q < 4; ++q) rs = dot8(rs, wl[(j*4 + q)*512 + t], hv[q]);
      rs = reduce8(rs);
      pb = (ks == 5 + j) ? rs : pb;
    }

    pre[preS + ks]     = pa;
    pre[preS + 8 + ks] = pb;
    __syncthreads();

    if (t < 256) {
      half2t x01 = __builtin_bit_cast(half2t, xq.x);  // i, f
      half2t x23 = __builtin_bit_cast(half2t, xq.y);  // g, o
      float vi = pre[t]       + (float)x01[0];
      float vf = pre[256 + t] + (float)x01[1];
      float vg = pre[512 + t] + (float)x23[0];
      float vo = pre[768 + t] + (float)x23[1];
      float ig = sigmoid_f(vi);
      float fg = sigmoid_f(vf);
      float gg = tanh_f(vg);
      float og = sigmoid_f(vo);
      cst = fg*cst + ig*gg;
      float hval = og*tanh_f(cst);
      f16 hf = (f16)hval;
      #pragma unroll
      for (int cpy = 0; cpy < 4; ++cpy) hrep[cpy*264 + t] = hf;
      outp[(size_t)s*512 + t] = hf;
    }
    __syncthreads();
  }
}

// ---------------- mean pool + k,v projection ----------------
__global__ __launch_bounds__(256) void pool_kv_kernel(
    const f16* __restrict__ out_sum, const int* __restrict__ len_sum,
    const float* __restrict__ Wk, const float* __restrict__ Wv,
    float* __restrict__ kb, float* __restrict__ vb)
{
  const int b = blockIdx.x, t = threadIdx.x;
  __shared__ float sv[512];
  int len = len_sum[b]; if (len < 1) len = 1;
  float a0 = 0.f, a1 = 0.f;
  for (int s = 0; s < len; ++s) {
    const f16* row = out_sum + ((size_t)b*SSUM + s)*512;
    a0 += (float)row[t];
    a1 += (float)row[t+256];
  }
  float inv = 1.f/(float)len;
  sv[t] = a0*inv; sv[t+256] = a1*inv;
  __syncthreads();
  #pragma unroll
  for (int half = 0; half < 2; ++half) {
    int o = t + half*256;
    int h = o >> 7, dh = o & 127;
    const float* wkp = Wk + (size_t)h*512*128 + dh;
    const float* wvp = Wv + (size_t)h*512*128 + dh;
    float ak = 0.f, av = 0.f;
    for (int e2 = 0; e2 < 512; ++e2) {
      float sve = sv[e2];
      ak += sve*wkp[(size_t)e2*128];
      av += sve*wvp[(size_t)e2*128];
    }
    kb[((size_t)h*32 + b)*128 + dh] = ak;
    vb[((size_t)h*32 + b)*128 + dh] = av;
  }
}

// ---------------- scores + softmax ----------------
__global__ __launch_bounds__(256) void attn_kernel(
    const float* __restrict__ q, const float* __restrict__ kb, float* __restrict__ attn)
{
  const int hb = blockIdx.x;          // h*32 + b
  const int h = hb >> 5, b = hb & 31;
  const int t = threadIdx.x;
  __shared__ __align__(16) float kk[128];
  __shared__ float red[4];
  if (t < 128) kk[t] = kb[(size_t)hb*128 + t];
  __syncthreads();
  float vals[4];
  #pragma unroll
  for (int i = 0; i < 4; ++i) {
    int s = t + i*256;
    const float4* qp = (const float4*)(q + ((size_t)b*1024 + s)*512 + h*128);
    const float4* kp = (const float4*)kk;
    float a = 0.f;
    #pragma unroll
    for (int e2 = 0; e2 < 32; ++e2) {
      float4 qq = qp[e2], kx = kp[e2];
      a += qq.x*kx.x + qq.y*kx.y + qq.z*kx.z + qq.w*kx.w;
    }
    vals[i] = a;
  }
  float m = fmaxf(fmaxf(vals[0], vals[1]), fmaxf(vals[2], vals[3]));
  for (int o = 1; o < 64; o <<= 1) m = fmaxf(m, __shfl_xor(m, o));
  if ((t & 63) == 0) red[t >> 6] = m;
  __syncthreads();
  m = fmaxf(fmaxf(red[0], red[1]), fmaxf(red[2], red[3]));
  __syncthreads();
  float ex[4], lsum = 0.f;
  #pragma unroll
  for (int i = 0; i < 4; ++i) { ex[i] = __expf(vals[i] - m); lsum += ex[i]; }
  for (int o = 1; o < 64; o <<= 1) lsum += __shfl_xor(lsum, o);
  if ((t & 63) == 0) red[t >> 6] = lsum;
  __syncthreads();
  float inv = 1.f/(red[0] + red[1] + red[2] + red[3]);
  #pragma unroll
  for (int i = 0; i < 4; ++i) attn[(size_t)hb*1024 + t + i*256] = ex[i]*inv;
}

// ---------------- final: out = q + attn * v ----------------
__global__ __launch_bounds__(256) void final_kernel(
    float* __restrict__ out, const float* __restrict__ attn, const float* __restrict__ vb)
{
  const size_t TOT4 = (size_t)32*1024*512/4;
  const size_t stride = (size_t)gridDim.x*blockDim.x;
  for (size_t i = (size_t)blockIdx.x*blockDim.x + threadIdx.x; i < TOT4; i += stride) {
    int c4 = (int)(i & 127);
    int h = c4 >> 5;
    size_t srow = i >> 7;
    int b = (int)(srow >> 10), s = (int)(srow & 1023);
    float a = attn[((size_t)h*32 + b)*1024 + s];
    float4 vv = ((const float4*)vb)[((size_t)h*32 + b)*32 + (c4 & 31)];
    float4 qq = ((float4*)out)[i];
    qq.x += a*vv.x; qq.y += a*vv.y; qq.z += a*vv.z; qq.w += a*vv.w;
    ((float4*)out)[i] = qq;
  }
}

// ---------------- launch ----------------
extern "C" void kernel_launch(void* const* d_in, const int* in_sizes, int n_in,
                              void* d_out, int out_size, void* d_ws, size_t ws_size,
                              hipStream_t stream)
{
  const float* in_raw = (const float*)d_in[0];
  const float* in_sum = (const float*)d_in[1];
  const int*  len_sum = (const int*)d_in[3];
  const float* rf_wih = (const float*)d_in[4];
  const float* rf_whh = (const float*)d_in[5];
  const float* rf_b   = (const float*)d_in[6];
  const float* rb_wih = (const float*)d_in[7];
  const float* rb_whh = (const float*)d_in[8];
  const float* rb_b   = (const float*)d_in[9];
  const float* sf_wih = (const float*)d_in[10];
  const float* sf_whh = (const float*)d_in[11];
  const float* sf_b   = (const float*)d_in[12];
  const float* sb_wih = (const float*)d_in[13];
  const float* sb_whh = (const float*)d_in[14];
  const float* sb_b   = (const float*)d_in[15];
  const float* wq     = (const float*)d_in[16];
  const float* wk     = (const float*)d_in[17];
  const float* wv     = (const float*)d_in[18];

  if (ws_size < WS_NEED) return;

  char* ws = (char*)d_ws;
  f16* xg_raw_p  = (f16*)(ws + OFF_XG_RAW);
  f16* xg_sum_p  = (f16*)(ws + OFF_XG_SUM);
  f16* out_raw_p = (f16*)(ws + OFF_OUT_RAW);
  f16* out_sum_p = (f16*)(ws + OFF_OUT_SUM);
  f16* a_raw_p   = (f16*)(ws + OFF_A_RAW);
  f16* a_sum_p   = (f16*)(ws + OFF_A_SUM);
  f16* bih_raw_p = (f16*)(ws + OFF_BIH_RAW);
  f16* bih_sum_p = (f16*)(ws + OFF_BIH_SUM);
  f16* whh16_p   = (f16*)(ws + OFF_WHH);
  f16* wq16_p    = (f16*)(ws + OFF_WQ);
  float* kb_p    = (float*)(ws + OFF_KB);
  float* vb_p    = (float*)(ws + OFF_VB);
  float* attn_p  = (float*)(ws + OFF_ATTN);
  float* qout    = (float*)d_out;

  pack_kernel<<<4096, 256, 0, stream>>>(
      in_raw, in_sum, rf_wih, rb_wih, sf_wih, sb_wih,
      rf_whh, rb_whh, sf_whh, sb_whh, wq,
      a_raw_p, a_sum_p, bih_raw_p, bih_sum_p, whh16_p, wq16_p);

  gemm_kernel<1><<<dim3(256, 16), 256, 0, stream>>>(
      a_raw_p, bih_raw_p, nullptr, xg_raw_p, rf_b, rb_b, KP, 0, (size_t)32*1024*1024);
  gemm_kernel<1><<<dim3(32, 16), 256, 0, stream>>>(
      a_sum_p, bih_sum_p, nullptr, xg_sum_p, sf_b, sb_b, KP, 0, (size_t)32*128*1024);

  lstm_kernel<<<128, 512, 0, stream>>>(whh16_p, xg_raw_p, xg_sum_p, out_raw_p, out_sum_p);

  gemm_kernel<0><<<dim3(256, 4), 256, 0, stream>>>(
      out_raw_p, wq16_p, qout, nullptr, nullptr, nullptr, 512, 512, 0);

  pool_kv_kernel<<<32, 256, 0, stream>>>(out_sum_p, len_sum, wk, wv, kb_p, vb_p);
  attn_kernel<<<128, 256, 0, stream>>>(qout, kb_p, attn_p);
  final_kernel<<<4096, 256, 0, stream>>>(qout, attn_p, vb_p);
}